// Round 1
// baseline (416.730 us; speedup 1.0000x reference)
//
#include <hip/hip_runtime.h>

// Input  x: (B=4, C=64, H=512, W=512) fp32
// Output: 4 bands (ll, lh, hl, hh), each (4, 64, 256, 256) fp32,
//         concatenated flat in d_out.
//
// Pure streaming kernel: 268 MB in + 268 MB out, zero reuse -> nontemporal.
// v2 layout change vs previous round: every memory instruction is fully
// lane-contiguous (16B loads at 16B lane stride, 8B stores at 8B lane
// stride), so coalescing never depends on cache-line retention between
// two strided NT loads (the previous kernel loaded 16B at 32B lane
// stride in pairs, which only achieves full line utilization if the
// evict-first NT lines survive until the sibling load).
//
// Each thread: 4 input cols x 2 rows (32 B in), 2 output cols x 4 bands
// (32 B out).

typedef float v2f __attribute__((ext_vector_type(2)));
typedef float v4f __attribute__((ext_vector_type(4)));

__global__ __launch_bounds__(256) void dwt_haar_kernel(
        const float* __restrict__ x, float* __restrict__ out) {
    const long long tid = (long long)blockIdx.x * blockDim.x + threadIdx.x;
    // total threads = B*C*outH * (outW/2) = 4*64*256 * 128 = 8,388,608
    const int       ow2 = (int)(tid & 127);  // which group of 2 output cols
    const long long row = tid >> 7;          // flattened (b, c, oh)
    const int       oh  = (int)(row & 255);
    const long long bc  = row >> 8;          // flattened (b, c)

    const float* in0 = x + bc * (512LL * 512LL) + (long long)(2 * oh) * 512LL
                         + (long long)ow2 * 4LL;

    // One 16B load per row, lane-contiguous across the wave (1KB/instr).
    const v4f r0 = __builtin_nontemporal_load((const v4f*)(in0));        // a0 b0 a1 b1
    const v4f r1 = __builtin_nontemporal_load((const v4f*)(in0 + 512));  // c0 d0 c1 d1

    const float s0 = r0.x + r0.y;   // a0+b0
    const float u0 = r0.x - r0.y;   // a0-b0
    const float t0 = r1.x + r1.y;   // c0+d0
    const float w0 = r1.x - r1.y;   // c0-d0
    const float s1 = r0.z + r0.w;   // a1+b1
    const float u1 = r0.z - r0.w;   // a1-b1
    const float t1 = r1.z + r1.w;   // c1+d1
    const float w1 = r1.z - r1.w;   // c1-d1

    v2f ll, lh, hl, hh;
    ll.x = (s0 + t0) * 0.5f;  ll.y = (s1 + t1) * 0.5f;
    lh.x = (s0 - t0) * 0.5f;  lh.y = (s1 - t1) * 0.5f;
    hl.x = (u0 + w0) * 0.5f;  hl.y = (u1 + w1) * 0.5f;
    hh.x = (u0 - w0) * 0.5f;  hh.y = (u1 - w1) * 0.5f;

    const long long band = 4LL * 64LL * 256LL * 256LL;  // 16,777,216 floats
    float* o = out + row * 256LL + (long long)ow2 * 2LL;
    __builtin_nontemporal_store(ll, (v2f*)(o));
    __builtin_nontemporal_store(lh, (v2f*)(o + band));
    __builtin_nontemporal_store(hl, (v2f*)(o + 2 * band));
    __builtin_nontemporal_store(hh, (v2f*)(o + 3 * band));
}

extern "C" void kernel_launch(void* const* d_in, const int* in_sizes, int n_in,
                              void* d_out, int out_size, void* d_ws, size_t ws_size,
                              hipStream_t stream) {
    const float* x   = (const float*)d_in[0];
    float*       out = (float*)d_out;
    const int block = 256;
    const int grid  = 8388608 / block;  // 32768
    dwt_haar_kernel<<<grid, block, 0, stream>>>(x, out);
}